// Round 1
// baseline (264.557 us; speedup 1.0000x reference)
//
#include <hip/hip_runtime.h>
#include <math.h>

// DETR HungarianMatcher cost matrix.
// N = bs*Q = 14400, T = 4096, C = 91. Output [N,T] fp32 = 236 MB -> write-BW bound.
//
// R4: contiguous-slab stores.
//  - block = full row width (TPB*TVEC = 4096 = T) x NROWS=8 rows
//    -> each block writes 128 KB CONTIGUOUS (rows are adjacent in [N,T] row-major),
//       streamed in address order; grid (1,1800) = 7.03 blocks/CU.
//  - class-cost table staged once per row-group (was 4x redundant at grid.x=4)
//  - store pointer incremented by T per row (no per-row 64-bit mul)
//  - per-target state in fully-unrolled constant-index arrays (SROA -> registers)
//  - single v_rcp per element: inter/uni + uni/ea = (inter*ea + uni^2)/(uni*ea)
//  - min3/max3 center/size box math, reuses L1 |dx|,|dy| (~26 VALU/elem)
//  - nontemporal float4 stores (write-once 236 MB stream)
//  - LDS class table padded to stride 96

#define ALPHA_  0.25f
#define EPS_    1e-8f

#define TPB    1024  // threads per block (16 waves)
#define TVEC   4     // targets per thread (one float4 store)
#define NROWS  8     // pred rows per block
#define CPAD   96    // padded class stride (C = 91 actual)

typedef float f32x4 __attribute__((ext_vector_type(4)));

__device__ __forceinline__ float fast_rcp(float x) {
    return __builtin_amdgcn_rcpf(x);
}

__global__ __launch_bounds__(TPB) void matcher_cost_kernel(
    const float* __restrict__ logits,  // [N, C]
    const float* __restrict__ pboxes,  // [N, 4] cxcywh
    const int*   __restrict__ tids,    // [T]
    const float* __restrict__ tboxes,  // [T, 4] cxcywh
    float* __restrict__ out,           // [N, T]
    int N, int C, int T)
{
    __shared__ float lds_cc[NROWS * CPAD];  // per-row class-cost table (3 KB)

    const int nbase = blockIdx.y * NROWS;
    const int rows  = min(NROWS, N - nbase);

    // ---- Stage class-cost table: cc[r][c] = pos - neg, focal-style ----
    for (int i = threadIdx.x; i < NROWS * CPAD; i += TPB) {
        const int r = i / CPAD;          // compile-time const divisor -> magic mul
        const int c = i - r * CPAD;
        if (r < rows && c < C) {
            const float x  = logits[(size_t)(nbase + r) * C + c];
            const float p  = fast_rcp(1.0f + __expf(-x));   // sigmoid
            const float om = 1.0f - p;
            const float pos = ALPHA_ * om * om * (-__logf(p + EPS_));
            const float neg = (1.0f - ALPHA_) * p * p * (-__logf(om + EPS_));
            lds_cc[i] = pos - neg;
        }
    }
    __syncthreads();

    const int t0 = blockIdx.x * (TPB * TVEC) + threadIdx.x * TVEC;
    if (t0 + TVEC > T) return;   // T = 4096 = TPB*TVEC: never taken; no barriers below

    // ---- This thread's 4 targets (constant-index arrays -> registers) ----
    const int4 id4 = *(const int4*)(tids + t0);
    int tid_[TVEC] = { id4.x, id4.y, id4.z, id4.w };

    float tcx[TVEC], tcy[TVEC], tw_[TVEC], th_[TVEC];
    float twh[TVEC], thh[TVEC], ta_[TVEC];
#pragma unroll
    for (int j = 0; j < TVEC; ++j) {
        const float4 tb = *(const float4*)(tboxes + (size_t)(t0 + j) * 4);
        tcx[j] = tb.x;  tcy[j] = tb.y;
        tw_[j] = tb.z;  th_[j] = tb.w;
        twh[j] = 0.5f * tb.z;
        thh[j] = 0.5f * tb.w;
        ta_[j] = tb.z * tb.w;
    }

    float* optr = out + (size_t)nbase * T + t0;

#pragma unroll 2
    for (int r = 0; r < rows; ++r) {
        const int n = nbase + r;
        const float4 pb = *(const float4*)(pboxes + (size_t)n * 4);  // uniform addr
        const float pcx = pb.x, pcy = pb.y, pw = pb.z, ph = pb.w;
        const float pwh = 0.5f * pw, phh = 0.5f * ph;
        const float pa  = pw * ph;
        const float* ccrow = &lds_cc[r * CPAD];

        f32x4 o;
#pragma unroll
        for (int j = 0; j < TVEC; ++j) {
            const float adx = fabsf(pcx - tcx[j]);
            const float ady = fabsf(pcy - tcy[j]);
            const float l1  = adx + ady + fabsf(pw - tw_[j]) + fabsf(ph - th_[j]);
            const float sx  = pwh + twh[j], sy = phh + thh[j];
            // overlap along an axis: min(pw, tw, sx - |dx|); enclosure: max(pw, tw, sx + |dx|)
            const float iw = fmaxf(fminf(fminf(pw, tw_[j]), sx - adx), 0.0f);
            const float ih = fmaxf(fminf(fminf(ph, th_[j]), sy - ady), 0.0f);
            const float ew = fmaxf(fmaxf(pw, tw_[j]), sx + adx);
            const float eh = fmaxf(fmaxf(ph, th_[j]), sy + ady);
            const float inter = iw * ih;
            const float uni   = pa + ta_[j] - inter;
            const float ea    = ew * eh;
            // g = inter/uni + uni/ea ; giou = g - 1
            const float num = fmaf(inter, ea, uni * uni);
            const float g   = num * fast_rcp(uni * ea);
            const float cc  = ccrow[tid_[j]];
            o[j] = fmaf(5.0f, l1, fmaf(2.0f, cc, fmaf(-2.0f, g, 2.0f)));
        }

        __builtin_nontemporal_store(o, (f32x4*)optr);
        optr += T;
    }
}

extern "C" void kernel_launch(void* const* d_in, const int* in_sizes, int n_in,
                              void* d_out, int out_size, void* d_ws, size_t ws_size,
                              hipStream_t stream) {
    const float* logits = (const float*)d_in[0];  // [N, C]
    const float* pboxes = (const float*)d_in[1];  // [N, 4]
    const int*   tids   = (const int*)  d_in[2];  // [T]
    const float* tboxes = (const float*)d_in[3];  // [T, 4]
    float* out = (float*)d_out;

    const int N = in_sizes[1] / 4;          // 14400
    const int C = in_sizes[0] / N;          // 91
    const int T = in_sizes[2];              // 4096

    dim3 grid((T + TPB * TVEC - 1) / (TPB * TVEC),   // 1
              (N + NROWS - 1) / NROWS);              // 1800
    matcher_cost_kernel<<<grid, TPB, 0, stream>>>(logits, pboxes, tids, tboxes,
                                                  out, N, C, T);
}

// Round 2
// 258.829 us; speedup vs baseline: 1.0221x; 1.0221x over previous
//
#include <hip/hip_runtime.h>
#include <math.h>

// DETR HungarianMatcher cost matrix.
// N = bs*Q = 14400, T = 4096, C = 91. Output [N,T] fp32 = 236 MB -> write-BW bound.
//
// R5: R4 with nontemporal store policy removed (single-variable probe).
//  Theory: nt (no-allocate/evict-early in TCC) demotes the 236 MB write stream
//  to a ~2 TB/s drain path; plain stores (what fillBuffer uses) hit 6.4 TB/s.
//  Everything else byte-identical to R4:
//  - block = full row width (TPB*TVEC = 4096 = T) x NROWS=8 rows
//    -> each block writes 128 KB contiguous; grid (1,1800) = 7.03 blocks/CU.
//  - class-cost table staged once per row-group
//  - store pointer incremented by T per row (no per-row 64-bit mul)
//  - per-target state in fully-unrolled constant-index arrays (SROA -> registers)
//  - single v_rcp per element: inter/uni + uni/ea = (inter*ea + uni^2)/(uni*ea)
//  - min3/max3 center/size box math, reuses L1 |dx|,|dy| (~30 VALU/elem)
//  - LDS class table padded to stride 96

#define ALPHA_  0.25f
#define EPS_    1e-8f

#define TPB    1024  // threads per block (16 waves)
#define TVEC   4     // targets per thread (one float4 store)
#define NROWS  8     // pred rows per block
#define CPAD   96    // padded class stride (C = 91 actual)

typedef float f32x4 __attribute__((ext_vector_type(4)));

__device__ __forceinline__ float fast_rcp(float x) {
    return __builtin_amdgcn_rcpf(x);
}

__global__ __launch_bounds__(TPB) void matcher_cost_kernel(
    const float* __restrict__ logits,  // [N, C]
    const float* __restrict__ pboxes,  // [N, 4] cxcywh
    const int*   __restrict__ tids,    // [T]
    const float* __restrict__ tboxes,  // [T, 4] cxcywh
    float* __restrict__ out,           // [N, T]
    int N, int C, int T)
{
    __shared__ float lds_cc[NROWS * CPAD];  // per-row class-cost table (3 KB)

    const int nbase = blockIdx.y * NROWS;
    const int rows  = min(NROWS, N - nbase);

    // ---- Stage class-cost table: cc[r][c] = pos - neg, focal-style ----
    for (int i = threadIdx.x; i < NROWS * CPAD; i += TPB) {
        const int r = i / CPAD;          // compile-time const divisor -> magic mul
        const int c = i - r * CPAD;
        if (r < rows && c < C) {
            const float x  = logits[(size_t)(nbase + r) * C + c];
            const float p  = fast_rcp(1.0f + __expf(-x));   // sigmoid
            const float om = 1.0f - p;
            const float pos = ALPHA_ * om * om * (-__logf(p + EPS_));
            const float neg = (1.0f - ALPHA_) * p * p * (-__logf(om + EPS_));
            lds_cc[i] = pos - neg;
        }
    }
    __syncthreads();

    const int t0 = blockIdx.x * (TPB * TVEC) + threadIdx.x * TVEC;
    if (t0 + TVEC > T) return;   // T = 4096 = TPB*TVEC: never taken; no barriers below

    // ---- This thread's 4 targets (constant-index arrays -> registers) ----
    const int4 id4 = *(const int4*)(tids + t0);
    int tid_[TVEC] = { id4.x, id4.y, id4.z, id4.w };

    float tcx[TVEC], tcy[TVEC], tw_[TVEC], th_[TVEC];
    float twh[TVEC], thh[TVEC], ta_[TVEC];
#pragma unroll
    for (int j = 0; j < TVEC; ++j) {
        const float4 tb = *(const float4*)(tboxes + (size_t)(t0 + j) * 4);
        tcx[j] = tb.x;  tcy[j] = tb.y;
        tw_[j] = tb.z;  th_[j] = tb.w;
        twh[j] = 0.5f * tb.z;
        thh[j] = 0.5f * tb.w;
        ta_[j] = tb.z * tb.w;
    }

    float* optr = out + (size_t)nbase * T + t0;

#pragma unroll 2
    for (int r = 0; r < rows; ++r) {
        const int n = nbase + r;
        const float4 pb = *(const float4*)(pboxes + (size_t)n * 4);  // uniform addr
        const float pcx = pb.x, pcy = pb.y, pw = pb.z, ph = pb.w;
        const float pwh = 0.5f * pw, phh = 0.5f * ph;
        const float pa  = pw * ph;
        const float* ccrow = &lds_cc[r * CPAD];

        f32x4 o;
#pragma unroll
        for (int j = 0; j < TVEC; ++j) {
            const float adx = fabsf(pcx - tcx[j]);
            const float ady = fabsf(pcy - tcy[j]);
            const float l1  = adx + ady + fabsf(pw - tw_[j]) + fabsf(ph - th_[j]);
            const float sx  = pwh + twh[j], sy = phh + thh[j];
            // overlap along an axis: min(pw, tw, sx - |dx|); enclosure: max(pw, tw, sx + |dx|)
            const float iw = fmaxf(fminf(fminf(pw, tw_[j]), sx - adx), 0.0f);
            const float ih = fmaxf(fminf(fminf(ph, th_[j]), sy - ady), 0.0f);
            const float ew = fmaxf(fmaxf(pw, tw_[j]), sx + adx);
            const float eh = fmaxf(fmaxf(ph, th_[j]), sy + ady);
            const float inter = iw * ih;
            const float uni   = pa + ta_[j] - inter;
            const float ea    = ew * eh;
            // g = inter/uni + uni/ea ; giou = g - 1
            const float num = fmaf(inter, ea, uni * uni);
            const float g   = num * fast_rcp(uni * ea);
            const float cc  = ccrow[tid_[j]];
            o[j] = fmaf(5.0f, l1, fmaf(2.0f, cc, fmaf(-2.0f, g, 2.0f)));
        }

        *(f32x4*)optr = o;   // plain store (was nontemporal) -- single-variable probe
        optr += T;
    }
}

extern "C" void kernel_launch(void* const* d_in, const int* in_sizes, int n_in,
                              void* d_out, int out_size, void* d_ws, size_t ws_size,
                              hipStream_t stream) {
    const float* logits = (const float*)d_in[0];  // [N, C]
    const float* pboxes = (const float*)d_in[1];  // [N, 4]
    const int*   tids   = (const int*)  d_in[2];  // [T]
    const float* tboxes = (const float*)d_in[3];  // [T, 4]
    float* out = (float*)d_out;

    const int N = in_sizes[1] / 4;          // 14400
    const int C = in_sizes[0] / N;          // 91
    const int T = in_sizes[2];              // 4096

    dim3 grid((T + TPB * TVEC - 1) / (TPB * TVEC),   // 1
              (N + NROWS - 1) / NROWS);              // 1800
    matcher_cost_kernel<<<grid, TPB, 0, stream>>>(logits, pboxes, tids, tboxes,
                                                  out, N, C, T);
}

// Round 3
// 258.767 us; speedup vs baseline: 1.0224x; 1.0002x over previous
//
#include <hip/hip_runtime.h>
#include <math.h>

// DETR HungarianMatcher cost matrix.
// N = bs*Q = 14400, T = 4096, C = 91. Output [N,T] fp32 = 236 MB.
//
// R6: occupancy probe. TVEC 4->2 halves per-thread target state
//     (target: VGPR <= 64 -> 8 waves/SIMD = 32 waves/CU, ~2x R4/R5).
//     Math byte-identical to R5; stores are coalesced float2 (full-line
//     coverage per wave). Discriminates latency/occupancy-bound (expect
//     dur 259 -> ~205) vs fixed harness floor (expect no change).
//  - TPB=512, NROWS=16, grid (4, 900) = 3600 blocks
//  - class-cost table in LDS, padded stride 96
//  - single v_rcp per element; min3/max3 box math reusing L1 |dx|,|dy|

#define ALPHA_  0.25f
#define EPS_    1e-8f

#define TPB    512   // threads per block (8 waves)
#define TVEC   2     // targets per thread (one float2 store)
#define NROWS  16    // pred rows per block
#define CPAD   96    // padded class stride (C = 91 actual)

typedef float f32x2 __attribute__((ext_vector_type(2)));

__device__ __forceinline__ float fast_rcp(float x) {
    return __builtin_amdgcn_rcpf(x);
}

__global__ __launch_bounds__(TPB) void matcher_cost_kernel(
    const float* __restrict__ logits,  // [N, C]
    const float* __restrict__ pboxes,  // [N, 4] cxcywh
    const int*   __restrict__ tids,    // [T]
    const float* __restrict__ tboxes,  // [T, 4] cxcywh
    float* __restrict__ out,           // [N, T]
    int N, int C, int T)
{
    __shared__ float lds_cc[NROWS * CPAD];  // per-row class-cost table (6 KB)

    const int nbase = blockIdx.y * NROWS;
    const int rows  = min(NROWS, N - nbase);

    // ---- Stage class-cost table: cc[r][c] = pos - neg, focal-style ----
    for (int i = threadIdx.x; i < NROWS * CPAD; i += TPB) {
        const int r = i / CPAD;          // compile-time const divisor -> magic mul
        const int c = i - r * CPAD;
        if (r < rows && c < C) {
            const float x  = logits[(size_t)(nbase + r) * C + c];
            const float p  = fast_rcp(1.0f + __expf(-x));   // sigmoid
            const float om = 1.0f - p;
            const float pos = ALPHA_ * om * om * (-__logf(p + EPS_));
            const float neg = (1.0f - ALPHA_) * p * p * (-__logf(om + EPS_));
            lds_cc[i] = pos - neg;
        }
    }
    __syncthreads();

    const int t0 = blockIdx.x * (TPB * TVEC) + threadIdx.x * TVEC;
    if (t0 + TVEC > T) return;   // T = 4096 = gridX*TPB*TVEC: never taken

    // ---- This thread's 2 targets (constant-index arrays -> registers) ----
    const int2 id2 = *(const int2*)(tids + t0);
    int tid_[TVEC] = { id2.x, id2.y };

    float tcx[TVEC], tcy[TVEC], tw_[TVEC], th_[TVEC];
    float twh[TVEC], thh[TVEC], ta_[TVEC];
#pragma unroll
    for (int j = 0; j < TVEC; ++j) {
        const float4 tb = *(const float4*)(tboxes + (size_t)(t0 + j) * 4);
        tcx[j] = tb.x;  tcy[j] = tb.y;
        tw_[j] = tb.z;  th_[j] = tb.w;
        twh[j] = 0.5f * tb.z;
        thh[j] = 0.5f * tb.w;
        ta_[j] = tb.z * tb.w;
    }

    float* optr = out + (size_t)nbase * T + t0;

    for (int r = 0; r < rows; ++r) {
        const int n = nbase + r;
        const float4 pb = *(const float4*)(pboxes + (size_t)n * 4);  // uniform addr
        const float pcx = pb.x, pcy = pb.y, pw = pb.z, ph = pb.w;
        const float pwh = 0.5f * pw, phh = 0.5f * ph;
        const float pa  = pw * ph;
        const float* ccrow = &lds_cc[r * CPAD];

        f32x2 o;
#pragma unroll
        for (int j = 0; j < TVEC; ++j) {
            const float adx = fabsf(pcx - tcx[j]);
            const float ady = fabsf(pcy - tcy[j]);
            const float l1  = adx + ady + fabsf(pw - tw_[j]) + fabsf(ph - th_[j]);
            const float sx  = pwh + twh[j], sy = phh + thh[j];
            // overlap along an axis: min(pw, tw, sx - |dx|); enclosure: max(pw, tw, sx + |dx|)
            const float iw = fmaxf(fminf(fminf(pw, tw_[j]), sx - adx), 0.0f);
            const float ih = fmaxf(fminf(fminf(ph, th_[j]), sy - ady), 0.0f);
            const float ew = fmaxf(fmaxf(pw, tw_[j]), sx + adx);
            const float eh = fmaxf(fmaxf(ph, th_[j]), sy + ady);
            const float inter = iw * ih;
            const float uni   = pa + ta_[j] - inter;
            const float ea    = ew * eh;
            // g = inter/uni + uni/ea ; giou = g - 1
            const float num = fmaf(inter, ea, uni * uni);
            const float g   = num * fast_rcp(uni * ea);
            const float cc  = ccrow[tid_[j]];
            o[j] = fmaf(5.0f, l1, fmaf(2.0f, cc, fmaf(-2.0f, g, 2.0f)));
        }

        *(f32x2*)optr = o;
        optr += T;
    }
}

extern "C" void kernel_launch(void* const* d_in, const int* in_sizes, int n_in,
                              void* d_out, int out_size, void* d_ws, size_t ws_size,
                              hipStream_t stream) {
    const float* logits = (const float*)d_in[0];  // [N, C]
    const float* pboxes = (const float*)d_in[1];  // [N, 4]
    const int*   tids   = (const int*)  d_in[2];  // [T]
    const float* tboxes = (const float*)d_in[3];  // [T, 4]
    float* out = (float*)d_out;

    const int N = in_sizes[1] / 4;          // 14400
    const int C = in_sizes[0] / N;          // 91
    const int T = in_sizes[2];              // 4096

    dim3 grid((T + TPB * TVEC - 1) / (TPB * TVEC),   // 4
              (N + NROWS - 1) / NROWS);              // 900
    matcher_cost_kernel<<<grid, TPB, 0, stream>>>(logits, pboxes, tids, tboxes,
                                                  out, N, C, T);
}